// Round 15
// baseline (143.395 us; speedup 1.0000x reference)
//
#include <hip/hip_runtime.h>

typedef _Float16 f16;
typedef _Float16 f16x8 __attribute__((ext_vector_type(8)));
typedef _Float16 f16x4 __attribute__((ext_vector_type(4)));
typedef float f32x4 __attribute__((ext_vector_type(4)));
typedef float f32x16 __attribute__((ext_vector_type(16)));
typedef unsigned short ushort_t;
typedef unsigned int uint_t;

#define SEQ 2048
#define DIM 128
#define KVBLK 64
#define NTMAX (SEQ / KVBLK)   // 32 k-tiles max
#define TILE_BYTES 16384      // 64x128 (or 128x64) f16 tile image
#define LOG2E 1.44269504f

typedef __attribute__((address_space(3))) char lds_char;
typedef __attribute__((address_space(1))) const char glb_char;

__device__ __forceinline__ void gload16(const void* g, void* l) {
  __builtin_amdgcn_global_load_lds((glb_char*)g, (lds_char*)l, 16, 0, 0);
}

// ---------------- scan: per-batch compaction of unmasked key indices ----------------
__global__ __launch_bounds__(64)
void scan_mask(const int* __restrict__ Mg, int* __restrict__ cidx, int* __restrict__ ncomp) {
  const int b = blockIdx.x;
  const int l = threadIdx.x;
  int m[32];
  int cnt = 0;
  const int* mp = Mg + (size_t)b * SEQ + l * 32;
#pragma unroll
  for (int j = 0; j < 32; ++j) { m[j] = mp[j]; cnt += (m[j] != 0) ? 1 : 0; }
  int inc = cnt;
  for (int ofs = 1; ofs < 64; ofs <<= 1) {
    int v = __shfl_up(inc, ofs);
    if (l >= ofs) inc += v;
  }
  int pos = inc - cnt;
  int* cp = cidx + (size_t)b * SEQ;
  for (int j = 0; j < 32; ++j)
    if (m[j] != 0) cp[pos++] = l * 32 + j;
  if (l == 63) ncomp[b] = inc;
}

// ------- merged pre-pass: blk<2048 -> K tile image; blk>=2048 -> V^T tile image -------
// K:  f16 (krow,d) -> byte  krow*256 + (((d>>3) ^ (krow&15))<<4) + (d&7)*2
// Vt: f16 (k,dv)   -> byte  dv*128  + (((k>>3) ^ (dv&7))<<4)  + (k&7)*2
__global__ __launch_bounds__(256)
void prep_kv(const float* __restrict__ Kg, char* __restrict__ Kws,
             const float* __restrict__ Vg, char* __restrict__ Vws,
             const int* __restrict__ cidx, const int* __restrict__ ncomp) {
  __shared__ ushort_t Vs[KVBLK * 133];
  const int tid  = threadIdx.x;
  const int raw  = blockIdx.x;
  const bool isV = raw >= 2048;
  const int blk  = isV ? raw - 2048 : raw;   // head*32 + t
  const int head = blk >> 5, t = blk & 31;
  const int b    = head >> 4;
  const int nc   = ncomp[b];
  if (t >= ((nc + 63) >> 6)) return;
  const int* cp = cidx + (size_t)b * SEQ;

  if (!isV) {
    const float* hin = Kg + (size_t)head * SEQ * DIM;
    char* out = Kws + (size_t)blk * TILE_BYTES;
#pragma unroll
    for (int i = 0; i < 4; ++i) {
      int u = i * 256 + tid;
      int krow = u >> 4;
      int un   = u & 15;
      int kidx = t * 64 + krow;
      union { f16 h[8]; uint4 u4; } c;
      if (kidx < nc) {
        const float* p = hin + (size_t)cp[kidx] * DIM + un * 8;
        float4 a = *(const float4*)p;
        float4 bq = *(const float4*)(p + 4);
        c.h[0]=(f16)a.x;  c.h[1]=(f16)a.y;  c.h[2]=(f16)a.z;  c.h[3]=(f16)a.w;
        c.h[4]=(f16)bq.x; c.h[5]=(f16)bq.y; c.h[6]=(f16)bq.z; c.h[7]=(f16)bq.w;
      } else {
        c.u4 = uint4{0, 0, 0, 0};
      }
      *(uint4*)(out + krow * 256 + ((un ^ (krow & 15)) << 4)) = c.u4;
    }
  } else {
    const float* hin = Vg + (size_t)head * SEQ * DIM;
    char* out = Vws + (size_t)blk * TILE_BYTES;
#pragma unroll
    for (int i = 0; i < 4; ++i) {
      int u = i * 256 + tid;
      int k  = u >> 4;
      int d0 = (u & 15) * 8;
      int kidx = t * 64 + k;
      f16 h[8];
      if (kidx < nc) {
        const float* p = hin + (size_t)cp[kidx] * DIM + d0;
        float4 a = *(const float4*)p;
        float4 bq = *(const float4*)(p + 4);
        h[0]=(f16)a.x;  h[1]=(f16)a.y;  h[2]=(f16)a.z;  h[3]=(f16)a.w;
        h[4]=(f16)bq.x; h[5]=(f16)bq.y; h[6]=(f16)bq.z; h[7]=(f16)bq.w;
      } else {
#pragma unroll
        for (int j = 0; j < 8; ++j) h[j] = (f16)0.f;
      }
#pragma unroll
      for (int j = 0; j < 8; ++j)
        Vs[k * 133 + d0 + j] = __builtin_bit_cast(ushort_t, h[j]);
    }
    __syncthreads();
#pragma unroll
    for (int i = 0; i < 4; ++i) {
      int u = i * 256 + tid;
      int d  = u >> 3;
      int un = u & 7;
      union { f16 h[8]; uint4 u4; } c;
#pragma unroll
      for (int j = 0; j < 8; ++j)
        c.h[j] = __builtin_bit_cast(f16, Vs[(un * 8 + j) * 133 + d]);
      *(uint4*)(out + d * 128 + ((un ^ (d & 7)) << 4)) = c.u4;
    }
  }
}

// ---- build PV A-fragments from packed P (prev tile): pa[ks][j] = P[q32][16ks+8h+j] ----
__device__ __forceinline__ void build_paf(const uint_t pkA[2][4], const uint_t pkB[2][4],
                                          f16x8 paf[4], int h) {
#pragma unroll
  for (int ks = 0; ks < 4; ++ks) {
    const int sk = ks & 1, tt = ks >> 1;
    uint_t Ao = h ? pkA[tt][2 * sk + 1] : pkA[tt][2 * sk];
    uint_t Bo = h ? pkB[tt][2 * sk + 1] : pkB[tt][2 * sk];
    uint_t As = h ? pkA[tt][2 * sk]     : pkA[tt][2 * sk + 1];
    uint_t Bs = h ? pkB[tt][2 * sk]     : pkB[tt][2 * sk + 1];
    uint_t Ax = (uint_t)__shfl_xor((int)As, 32);
    uint_t Bx = (uint_t)__shfl_xor((int)Bs, 32);
    union { uint_t u[4]; f16x8 v; } pa;
    pa.u[0] = h ? Ax : Ao;
    pa.u[1] = h ? Bx : Bo;
    pa.u[2] = h ? Ao : Ax;
    pa.u[3] = h ? Bo : Bx;
    paf[ks] = pa.v;
  }
}

// ---- PV MFMA block: 4 independent oacc chains ----
__device__ __forceinline__ void pv_mfma(const char* __restrict__ Vbuf,
                                        const f16x8 paf[4], f32x16 oacc[4],
                                        int q32, int h) {
  __builtin_amdgcn_s_setprio(1);
#pragma unroll
  for (int ks = 0; ks < 4; ++ks) {
#pragma unroll
    for (int dvt = 0; dvt < 4; ++dvt) {
      const int dv = dvt * 32 + q32;
      f16x8 vf = *(const f16x8*)(&Vbuf[dv * 128 + (((2 * ks + h) ^ (dv & 7)) << 4)]);
      oacc[dvt] = __builtin_amdgcn_mfma_f32_32x32x16_f16(vf, paf[ks], oacc[dvt], 0, 0, 0);
    }
  }
  __builtin_amdgcn_s_setprio(0);
}

// ------- main: 4 waves x QBLK32 (128 q-rows/block), 2 blocks/CU, exp2 domain -------
__global__ __launch_bounds__(256, 2)
void attn_main32(const float* __restrict__ Qg, const char* __restrict__ Kws,
                 const char* __restrict__ Vws, const int* __restrict__ ncomp,
                 float* __restrict__ Og) {
  __shared__ __align__(16) char Kb[2][TILE_BYTES];
  __shared__ __align__(16) char Vb[2][TILE_BYTES];

  const int tid  = threadIdx.x;
  const int lane = tid & 63;
  const int q32  = lane & 31;
  const int h    = lane >> 5;
  const int w    = tid >> 6;                     // wave 0..3

  // XCD grouping: 1024 blocks, XCD x gets heads [8x, 8x+8)
  const int bid  = blockIdx.x;                   // 0..1023
  const int nid  = (bid & 7) * 128 + (bid >> 3); // 0..1023
  const int head = nid >> 4;                     // 0..63
  const int qblk = nid & 15;                     // 0..15 (128 q-rows each)
  const size_t hbase = (size_t)head * SEQ * DIM;
  const int bb = head >> 4;

  const int nc  = ncomp[bb];
  const int ntb = (nc + 63) >> 6;

  const char* ktb = Kws + ((size_t)(head * NTMAX) << 14);
  const char* vtb = Vws + ((size_t)(head * NTMAX) << 14);

  const int qrow = qblk * 128 + w * 32 + q32;

  // Q fragments scaled by log2e: lane holds (Q*log2e)[qrow][d = 16c + 8h + j]
  f16x8 qf[8];
  {
    const float* qp = Qg + hbase + (size_t)qrow * DIM + h * 8;
#pragma unroll
    for (int c = 0; c < 8; ++c) {
      float4 a = *(const float4*)(qp + c * 16);
      float4 b = *(const float4*)(qp + c * 16 + 4);
      f16x8 f;
      f[0]=(f16)(a.x*LOG2E); f[1]=(f16)(a.y*LOG2E); f[2]=(f16)(a.z*LOG2E); f[3]=(f16)(a.w*LOG2E);
      f[4]=(f16)(b.x*LOG2E); f[5]=(f16)(b.y*LOG2E); f[6]=(f16)(b.z*LOG2E); f[7]=(f16)(b.w*LOG2E);
      qf[c] = f;
    }
  }

  f32x16 oacc[4];
#pragma unroll
  for (int dvt = 0; dvt < 4; ++dvt) oacc[dvt] = (f32x16)(0.f);
  float mrow = -INFINITY, lrow = 0.f;

  // packed P of the previous tile
  uint_t pkPA[2][4], pkPB[2][4];
#pragma unroll
  for (int t2 = 0; t2 < 2; ++t2)
#pragma unroll
    for (int m = 0; m < 4; ++m) { pkPA[t2][m] = 0; pkPB[t2][m] = 0; }

  // prologue: stage K(0)   (256 threads x 4 x 16B = 16KB)
#pragma unroll
  for (int i = 0; i < 4; ++i) {
    int u = i * 256 + tid;
    gload16(ktb + u * 16, &Kb[0][u * 16]);
  }

  int cur = 0;
  for (int t = 0; t < ntb; ++t) {
    // ---- stage K(t+1) into Kb[cur^1], V(t) into Vb[cur] ----
    {
      const int tn = (t + 1 == ntb) ? 0 : t + 1;
      const char* kt2 = ktb + ((size_t)tn << 14);
      const char* vt2 = vtb + ((size_t)t << 14);
      const int nb = cur ^ 1;
#pragma unroll
      for (int i = 0; i < 4; ++i) {
        int u = i * 256 + tid;
        gload16(kt2 + u * 16, &Kb[nb][u * 16]);
      }
#pragma unroll
      for (int i = 0; i < 4; ++i) {
        int u = i * 256 + tid;
        gload16(vt2 + u * 16, &Vb[cur][u * 16]);
      }
    }
    // K(t), V(t-1) were the 8 loads issued last iter; keep this iter's 8 in flight
    asm volatile("s_waitcnt vmcnt(8)" ::: "memory");
    __builtin_amdgcn_s_barrier();
    asm volatile("" ::: "memory");

    // ---- QK^T(t): two interleaved accumulator chains (scores in log2 domain) ----
    f32x16 s0, s1;
    {
      const int kb0 = t * 64;
      if (kb0 + 32 <= nc) {
        s0 = (f32x16)(0.f);
      } else {
#pragma unroll
        for (int ri = 0; ri < 16; ++ri)
          s0[ri] = (kb0 + (ri >> 2) * 8 + 4 * h + (ri & 3) < nc) ? 0.f : -1e9f;
      }
      const int kb1 = t * 64 + 32;
      if (kb1 + 32 <= nc) {
        s1 = (f32x16)(0.f);
      } else {
#pragma unroll
        for (int ri = 0; ri < 16; ++ri)
          s1[ri] = (kb1 + (ri >> 2) * 8 + 4 * h + (ri & 3) < nc) ? 0.f : -1e9f;
      }
      const int kr0 = q32,      sw0 = kr0 & 15;
      const int kr1 = 32 + q32, sw1 = kr1 & 15;
      __builtin_amdgcn_s_setprio(1);
#pragma unroll
      for (int c = 0; c < 8; ++c) {
        f16x8 k0 = *(const f16x8*)(&Kb[cur][kr0 * 256 + (((2 * c + h) ^ sw0) << 4)]);
        s0 = __builtin_amdgcn_mfma_f32_32x32x16_f16(k0, qf[c], s0, 0, 0, 0);
        f16x8 k1 = *(const f16x8*)(&Kb[cur][kr1 * 256 + (((2 * c + h) ^ sw1) << 4)]);
        s1 = __builtin_amdgcn_mfma_f32_32x32x16_f16(k1, qf[c], s1, 0, 0, 0);
      }
      __builtin_amdgcn_s_setprio(0);
    }

    // ---- PV(t-1): independent of QK(t)/SM(t) ----
    if (t > 0) {
      f16x8 paf[4];
      build_paf(pkPA, pkPB, paf, h);
      pv_mfma(&Vb[cur ^ 1][0], paf, oacc, q32, h);
    }

    // ---- SM(t): tree max, defer-max rescale, exp2, tree sum, pack ----
    {
      float mx[16];
#pragma unroll
      for (int r = 0; r < 16; ++r) mx[r] = fmaxf(s0[r], s1[r]);
#pragma unroll
      for (int r = 0; r < 8; ++r) mx[r] = fmaxf(mx[r], mx[r + 8]);
#pragma unroll
      for (int r = 0; r < 4; ++r) mx[r] = fmaxf(mx[r], mx[r + 4]);
      float pmax = fmaxf(fmaxf(mx[0], mx[1]), fmaxf(mx[2], mx[3]));
      pmax = fmaxf(pmax, __shfl_xor(pmax, 32));

      if (!__all(pmax - mrow <= 11.54f)) {       // defer-max (T13), log2 units
        float mnew = fmaxf(mrow, pmax);
        float scf = exp2f(mrow - mnew);
#pragma unroll
        for (int dvt = 0; dvt < 4; ++dvt)
#pragma unroll
          for (int r = 0; r < 16; ++r) oacc[dvt][r] *= scf;
        lrow *= scf;
        mrow = mnew;
      }

      float ps[16];
#pragma unroll
      for (int r = 0; r < 16; ++r) {
        s0[r] = exp2f(s0[r] - mrow);
        s1[r] = exp2f(s1[r] - mrow);
        ps[r] = s0[r] + s1[r];
      }
#pragma unroll
      for (int r = 0; r < 8; ++r) ps[r] += ps[r + 8];
#pragma unroll
      for (int r = 0; r < 4; ++r) ps[r] += ps[r + 4];
      float psum = (ps[0] + ps[1]) + (ps[2] + ps[3]);
      psum += __shfl_xor(psum, 32);
      lrow += psum;

#pragma unroll
      for (int m = 0; m < 4; ++m) {
        pkPA[0][m] = __builtin_bit_cast(uint_t,
            __builtin_amdgcn_cvt_pkrtz(s0[4 * m + 0], s0[4 * m + 1]));
        pkPB[0][m] = __builtin_bit_cast(uint_t,
            __builtin_amdgcn_cvt_pkrtz(s0[4 * m + 2], s0[4 * m + 3]));
        pkPA[1][m] = __builtin_bit_cast(uint_t,
            __builtin_amdgcn_cvt_pkrtz(s1[4 * m + 0], s1[4 * m + 1]));
        pkPB[1][m] = __builtin_bit_cast(uint_t,
            __builtin_amdgcn_cvt_pkrtz(s1[4 * m + 2], s1[4 * m + 3]));
      }
    }

    asm volatile("" ::: "memory");
    __builtin_amdgcn_s_barrier();
    asm volatile("" ::: "memory");
    cur ^= 1;
  }

  // ---- epilogue: drain V(ntb-1), final PV, normalize, store ----
  asm volatile("s_waitcnt vmcnt(0)" ::: "memory");
  __builtin_amdgcn_s_barrier();
  asm volatile("" ::: "memory");
  {
    f16x8 paf[4];
    build_paf(pkPA, pkPB, paf, h);
    pv_mfma(&Vb[cur ^ 1][0], paf, oacc, q32, h);
  }

  const float inv = 1.0f / lrow;
  float* op = Og + hbase + (size_t)qrow * DIM;
#pragma unroll
  for (int dvt = 0; dvt < 4; ++dvt)
#pragma unroll
    for (int rq = 0; rq < 4; ++rq) {
      float4 o4;
      o4.x = oacc[dvt][4 * rq + 0] * inv;
      o4.y = oacc[dvt][4 * rq + 1] * inv;
      o4.z = oacc[dvt][4 * rq + 2] * inv;
      o4.w = oacc[dvt][4 * rq + 3] * inv;
      *(float4*)(op + dvt * 32 + rq * 8 + h * 4) = o4;
    }
}

// ---------------- fallback (verified round-1 kernel) for small ws ----------------
#define QT 64
#define P_STRIDE 72
#define VT_STRIDE 76
typedef _Float16 f16x4_t __attribute__((ext_vector_type(4)));
__global__ __launch_bounds__(256, 2)
void attn_fwd_fb(const float* __restrict__ Qg, const float* __restrict__ Kg,
                 const float* __restrict__ Vg, const int* __restrict__ Mg,
                 float* __restrict__ Og) {
  __shared__ __align__(16) ushort_t K_lds[QT * DIM];
  __shared__ __align__(16) ushort_t Vt_lds[DIM * VT_STRIDE];
  __shared__ __align__(16) ushort_t P_lds[QT * P_STRIDE];
  __shared__ int M_lds[KVBLK];
  const int tid  = threadIdx.x;
  const int lane = tid & 63;
  const int w    = tid >> 6;
  const int li   = lane & 15;
  const int g    = lane >> 4;
  const int bid  = blockIdx.x;
  const int nid  = (bid & 7) * 256 + (bid >> 3);
  const int head = nid >> 5;
  const int qblk = nid & 31;
  const size_t hbase = (size_t)head * SEQ * DIM;
  const int bb = head >> 4;
  f16x8 qf[4];
  {
    const float* qp = Qg + hbase + (size_t)(qblk * QT + w * 16 + li) * DIM + g * 8;
#pragma unroll
    for (int d0 = 0; d0 < 4; ++d0) {
      float4 a = *(const float4*)(qp + d0 * 32);
      float4 b = *(const float4*)(qp + d0 * 32 + 4);
      f16x8 f;
      f[0]=(f16)a.x; f[1]=(f16)a.y; f[2]=(f16)a.z; f[3]=(f16)a.w;
      f[4]=(f16)b.x; f[5]=(f16)b.y; f[6]=(f16)b.z; f[7]=(f16)b.w;
      qf[d0] = f;
    }
  }
  float mrow[4], lrow[4];
  f32x4 oacc[8];
#pragma unroll
  for (int r = 0; r < 4; ++r) { mrow[r] = -INFINITY; lrow[r] = 0.f; }
#pragma unroll
  for (int dt = 0; dt < 8; ++dt) oacc[dt] = (f32x4)(0.f);
  for (int t = 0; t < NTMAX; ++t) {
    const int k0 = t * KVBLK;
    __syncthreads();
    {
      const float4* kgp = (const float4*)(Kg + hbase + (size_t)k0 * DIM);
#pragma unroll
      for (int rr = 0; rr < 8; ++rr) {
        int fi = rr * 256 + tid;
        int krow = fi >> 5;
        int d4 = fi & 31;
        float4 v = kgp[fi];
        union { f16 h[4]; uint2 u; } c;
        c.h[0]=(f16)v.x; c.h[1]=(f16)v.y; c.h[2]=(f16)v.z; c.h[3]=(f16)v.w;
        int off = krow * 256 + ((d4 * 8) ^ ((krow & 7) << 4));
        *(uint2*)((char*)K_lds + off) = c.u;
      }
    }
    {
      const float* vgp = Vg + hbase + (size_t)k0 * DIM;
#pragma unroll
      for (int rr = 0; rr < 16; ++rr) {
        int u = rr * 256 + tid;
        int d = u & 127;
        int k2 = (u >> 7) * 2;
        float v0 = vgp[(size_t)k2 * DIM + d];
        float v1 = vgp[(size_t)(k2 + 1) * DIM + d];
        union { f16 h[2]; unsigned int u32; } c;
        c.h[0]=(f16)v0; c.h[1]=(f16)v1;
        *(unsigned int*)(Vt_lds + d * VT_STRIDE + k2) = c.u32;
      }
    }
    if (tid < KVBLK) M_lds[tid] = Mg[(size_t)bb * SEQ + k0 + tid];
    __syncthreads();
    f32x4 sacc[4];
#pragma unroll
    for (int kt = 0; kt < 4; ++kt) sacc[kt] = (f32x4)(0.f);
#pragma unroll
    for (int kt = 0; kt < 4; ++kt) {
      const int krow = kt * 16 + li;
      const int swz = (krow & 7) << 4;
#pragma unroll
      for (int d0 = 0; d0 < 4; ++d0) {
        f16x8 kf = *(const f16x8*)((const char*)K_lds + krow * 256 + ((d0 * 64 + g * 16) ^ swz));
        sacc[kt] = __builtin_amdgcn_mfma_f32_16x16x32_f16(qf[d0], kf, sacc[kt], 0, 0, 0);
      }
    }
    float tmax[4] = {-INFINITY, -INFINITY, -INFINITY, -INFINITY};
#pragma unroll
    for (int kt = 0; kt < 4; ++kt) {
      const bool ok = (M_lds[kt * 16 + li] != 0);
#pragma unroll
      for (int r = 0; r < 4; ++r) {
        float sv = ok ? sacc[kt][r] : -1e9f;
        sacc[kt][r] = sv;
        tmax[r] = fmaxf(tmax[r], sv);
      }
    }
#pragma unroll
    for (int r = 0; r < 4; ++r) {
      tmax[r] = fmaxf(tmax[r], __shfl_xor(tmax[r], 1));
      tmax[r] = fmaxf(tmax[r], __shfl_xor(tmax[r], 2));
      tmax[r] = fmaxf(tmax[r], __shfl_xor(tmax[r], 4));
      tmax[r] = fmaxf(tmax[r], __shfl_xor(tmax[r], 8));
    }
    float sc[4], psum[4];
#pragma unroll
    for (int r = 0; r < 4; ++r) {
      float mnew = fmaxf(mrow[r], tmax[r]);
      sc[r] = __expf(mrow[r] - mnew);
      mrow[r] = mnew;
      psum[r] = 0.f;
    }
#pragma unroll
    for (int dt = 0; dt < 8; ++dt)
#pragma unroll
      for (int r = 0; r < 4; ++r) oacc[dt][r] *= sc[r];
#pragma unroll
    for (int kt = 0; kt < 4; ++kt) {
#pragma unroll
      for (int r = 0; r < 4; ++r) {
        float p = __expf(sacc[kt][r] - mrow[r]);
        psum[r] += p;
        P_lds[(w * 16 + g * 4 + r) * P_STRIDE + kt * 16 + li] =
            __builtin_bit_cast(ushort_t, (f16)p);
      }
    }
#pragma unroll
    for (int r = 0; r < 4; ++r) {
      psum[r] += __shfl_xor(psum[r], 1);
      psum[r] += __shfl_xor(psum[r], 2);
      psum[r] += __shfl_xor(psum[r], 4);
      psum[r] += __shfl_xor(psum[r], 8);
      lrow[r] = lrow[r] * sc[r] + psum[r];
    }
#pragma unroll
    for (int c = 0; c < 2; ++c) {
      f16x8 pa = *(const f16x8*)(P_lds + (w * 16 + li) * P_STRIDE + c * 32 + g * 8);
#pragma unroll
      for (int dt = 0; dt < 8; ++dt) {
        const ushort_t* vp = Vt_lds + (dt * 16 + li) * VT_STRIDE + c * 32 + g * 8;
        f16x4_t v0 = *(const f16x4_t*)vp;
        f16x4_t v1 = *(const f16x4_t*)(vp + 4);
        f16x8 vf;
        vf[0]=v0[0]; vf[1]=v0[1]; vf[2]=v0[2]; vf[3]=v0[3];
        vf[4]=v1[0]; vf[5]=v1[1]; vf[6]=v1[2]; vf[7]=v1[3];
        oacc[dt] = __builtin_amdgcn_mfma_f32_16x16x32_f16(pa, vf, oacc[dt], 0, 0, 0);
      }
    }
  }
#pragma unroll
  for (int r = 0; r < 4; ++r) {
    float inv = 1.0f / lrow[r];
    float* op = Og + hbase + (size_t)(qblk * QT + w * 16 + g * 4 + r) * DIM + li;
#pragma unroll
    for (int dt = 0; dt < 8; ++dt) op[dt * 16] = oacc[dt][r] * inv;
  }
}

extern "C" void kernel_launch(void* const* d_in, const int* in_sizes, int n_in,
                              void* d_out, int out_size, void* d_ws, size_t ws_size,
                              hipStream_t stream) {
  (void)in_sizes; (void)n_in; (void)out_size;
  const float* Q = (const float*)d_in[0];
  const float* K = (const float*)d_in[1];
  const float* V = (const float*)d_in[2];
  const int*   M = (const int*)d_in[3];
  float*       O = (float*)d_out;

  const size_t half = (size_t)2048 * TILE_BYTES;         // 33.5 MB each
  const size_t cidx_off  = 2 * half;
  const size_t ncomp_off = cidx_off + (size_t)4 * SEQ * sizeof(int);
  const size_t need = ncomp_off + 4 * sizeof(int);

  if (ws_size >= need) {
    char* Kws = (char*)d_ws;
    char* Vws = Kws + half;
    int*  cidx  = (int*)((char*)d_ws + cidx_off);
    int*  ncomp = (int*)((char*)d_ws + ncomp_off);
    scan_mask<<<dim3(4), dim3(64), 0, stream>>>(M, cidx, ncomp);
    prep_kv<<<dim3(4096), dim3(256), 0, stream>>>(K, Kws, V, Vws, cidx, ncomp);
    attn_main32<<<dim3(1024), dim3(256), 0, stream>>>(Q, Kws, Vws, ncomp, O);
  } else {
    attn_fwd_fb<<<dim3(2048), dim3(256), 0, stream>>>(Q, K, V, M, O);
  }
}

// Round 16
// 133.352 us; speedup vs baseline: 1.0753x; 1.0753x over previous
//
#include <hip/hip_runtime.h>

typedef _Float16 f16;
typedef _Float16 f16x8 __attribute__((ext_vector_type(8)));
typedef _Float16 f16x4 __attribute__((ext_vector_type(4)));
typedef float f32x4 __attribute__((ext_vector_type(4)));
typedef float f32x16 __attribute__((ext_vector_type(16)));
typedef unsigned short ushort_t;
typedef unsigned int uint_t;

#define SEQ 2048
#define DIM 128
#define KVBLK 64
#define NTMAX (SEQ / KVBLK)   // 32 k-tiles max
#define TILE_BYTES 16384      // 64x128 (or 128x64) f16 tile image

typedef __attribute__((address_space(3))) char lds_char;
typedef __attribute__((address_space(1))) const char glb_char;

__device__ __forceinline__ void gload16(const void* g, void* l) {
  __builtin_amdgcn_global_load_lds((glb_char*)g, (lds_char*)l, 16, 0, 0);
}

// ---------------- scan: per-batch compaction of unmasked key indices ----------------
__global__ __launch_bounds__(64)
void scan_mask(const int* __restrict__ Mg, int* __restrict__ cidx, int* __restrict__ ncomp) {
  const int b = blockIdx.x;
  const int l = threadIdx.x;
  int m[32];
  int cnt = 0;
  const int* mp = Mg + (size_t)b * SEQ + l * 32;
#pragma unroll
  for (int j = 0; j < 32; ++j) { m[j] = mp[j]; cnt += (m[j] != 0) ? 1 : 0; }
  int inc = cnt;
  for (int ofs = 1; ofs < 64; ofs <<= 1) {
    int v = __shfl_up(inc, ofs);
    if (l >= ofs) inc += v;
  }
  int pos = inc - cnt;
  int* cp = cidx + (size_t)b * SEQ;
  for (int j = 0; j < 32; ++j)
    if (m[j] != 0) cp[pos++] = l * 32 + j;
  if (l == 63) ncomp[b] = inc;
}

// ------- merged pre-pass: blk<2048 -> K tile image; blk>=2048 -> V^T tile image -------
// K:  f16 (krow,d) -> byte  krow*256 + (((d>>3) ^ (krow&15))<<4) + (d&7)*2
// Vt: f16 (k,dv)   -> byte  dv*128  + (((k>>3) ^ (dv&7))<<4)  + (k&7)*2
__global__ __launch_bounds__(256)
void prep_kv(const float* __restrict__ Kg, char* __restrict__ Kws,
             const float* __restrict__ Vg, char* __restrict__ Vws,
             const int* __restrict__ cidx, const int* __restrict__ ncomp) {
  __shared__ ushort_t Vs[KVBLK * 133];
  const int tid  = threadIdx.x;
  const int raw  = blockIdx.x;
  const bool isV = raw >= 2048;
  const int blk  = isV ? raw - 2048 : raw;   // head*32 + t
  const int head = blk >> 5, t = blk & 31;
  const int b    = head >> 4;
  const int nc   = ncomp[b];
  if (t >= ((nc + 63) >> 6)) return;
  const int* cp = cidx + (size_t)b * SEQ;

  if (!isV) {
    const float* hin = Kg + (size_t)head * SEQ * DIM;
    char* out = Kws + (size_t)blk * TILE_BYTES;
#pragma unroll
    for (int i = 0; i < 4; ++i) {
      int u = i * 256 + tid;
      int krow = u >> 4;
      int un   = u & 15;
      int kidx = t * 64 + krow;
      union { f16 h[8]; uint4 u4; } c;
      if (kidx < nc) {
        const float* p = hin + (size_t)cp[kidx] * DIM + un * 8;
        float4 a = *(const float4*)p;
        float4 bq = *(const float4*)(p + 4);
        c.h[0]=(f16)a.x;  c.h[1]=(f16)a.y;  c.h[2]=(f16)a.z;  c.h[3]=(f16)a.w;
        c.h[4]=(f16)bq.x; c.h[5]=(f16)bq.y; c.h[6]=(f16)bq.z; c.h[7]=(f16)bq.w;
      } else {
        c.u4 = uint4{0, 0, 0, 0};
      }
      *(uint4*)(out + krow * 256 + ((un ^ (krow & 15)) << 4)) = c.u4;
    }
  } else {
    const float* hin = Vg + (size_t)head * SEQ * DIM;
    char* out = Vws + (size_t)blk * TILE_BYTES;
#pragma unroll
    for (int i = 0; i < 4; ++i) {
      int u = i * 256 + tid;
      int k  = u >> 4;
      int d0 = (u & 15) * 8;
      int kidx = t * 64 + k;
      f16 h[8];
      if (kidx < nc) {
        const float* p = hin + (size_t)cp[kidx] * DIM + d0;
        float4 a = *(const float4*)p;
        float4 bq = *(const float4*)(p + 4);
        h[0]=(f16)a.x;  h[1]=(f16)a.y;  h[2]=(f16)a.z;  h[3]=(f16)a.w;
        h[4]=(f16)bq.x; h[5]=(f16)bq.y; h[6]=(f16)bq.z; h[7]=(f16)bq.w;
      } else {
#pragma unroll
        for (int j = 0; j < 8; ++j) h[j] = (f16)0.f;
      }
#pragma unroll
      for (int j = 0; j < 8; ++j)
        Vs[k * 133 + d0 + j] = __builtin_bit_cast(ushort_t, h[j]);
    }
    __syncthreads();
#pragma unroll
    for (int i = 0; i < 4; ++i) {
      int u = i * 256 + tid;
      int d  = u >> 3;
      int un = u & 7;
      union { f16 h[8]; uint4 u4; } c;
#pragma unroll
      for (int j = 0; j < 8; ++j)
        c.h[j] = __builtin_bit_cast(f16, Vs[(un * 8 + j) * 133 + d]);
      *(uint4*)(out + d * 128 + ((un ^ (d & 7)) << 4)) = c.u4;
    }
  }
}

// ---- build PV A-fragments from packed P (prev tile): pa[ks][j] = P[q32][16ks+8h+j] ----
__device__ __forceinline__ void build_paf(const uint_t pkA[2][4], const uint_t pkB[2][4],
                                          f16x8 paf[4], int h) {
#pragma unroll
  for (int ks = 0; ks < 4; ++ks) {
    const int sk = ks & 1, tt = ks >> 1;
    uint_t Ao = h ? pkA[tt][2 * sk + 1] : pkA[tt][2 * sk];
    uint_t Bo = h ? pkB[tt][2 * sk + 1] : pkB[tt][2 * sk];
    uint_t As = h ? pkA[tt][2 * sk]     : pkA[tt][2 * sk + 1];
    uint_t Bs = h ? pkB[tt][2 * sk]     : pkB[tt][2 * sk + 1];
    uint_t Ax = (uint_t)__shfl_xor((int)As, 32);
    uint_t Bx = (uint_t)__shfl_xor((int)Bs, 32);
    union { uint_t u[4]; f16x8 v; } pa;
    pa.u[0] = h ? Ax : Ao;
    pa.u[1] = h ? Bx : Bo;
    pa.u[2] = h ? Ao : Ax;
    pa.u[3] = h ? Bo : Bx;
    paf[ks] = pa.v;
  }
}

// ---- PV MFMA block: 4 independent oacc chains ----
__device__ __forceinline__ void pv_mfma(const char* __restrict__ Vbuf,
                                        const f16x8 paf[4], f32x16 oacc[4],
                                        int q32, int h) {
  __builtin_amdgcn_s_setprio(1);
#pragma unroll
  for (int ks = 0; ks < 4; ++ks) {
#pragma unroll
    for (int dvt = 0; dvt < 4; ++dvt) {
      const int dv = dvt * 32 + q32;
      f16x8 vf = *(const f16x8*)(&Vbuf[dv * 128 + (((2 * ks + h) ^ (dv & 7)) << 4)]);
      oacc[dvt] = __builtin_amdgcn_mfma_f32_32x32x16_f16(vf, paf[ks], oacc[dvt], 0, 0, 0);
    }
  }
  __builtin_amdgcn_s_setprio(0);
}

// ------- main: 4 waves x QBLK32 (128 q-rows/block), 2 independent blocks/CU -------
__global__ __launch_bounds__(256, 2)
void attn_main32(const float* __restrict__ Qg, const char* __restrict__ Kws,
                 const char* __restrict__ Vws, const int* __restrict__ ncomp,
                 float* __restrict__ Og) {
  __shared__ __align__(16) char Kb[2][TILE_BYTES];
  __shared__ __align__(16) char Vb[2][TILE_BYTES];

  const int tid  = threadIdx.x;
  const int lane = tid & 63;
  const int q32  = lane & 31;
  const int h    = lane >> 5;
  const int w    = tid >> 6;                     // wave 0..3

  // XCD grouping: 1024 blocks, XCD x gets heads [8x, 8x+8)
  const int bid  = blockIdx.x;                   // 0..1023
  const int nid  = (bid & 7) * 128 + (bid >> 3); // 0..1023
  const int head = nid >> 4;                     // 0..63
  const int qblk = nid & 15;                     // 0..15 (128 q-rows each)
  const size_t hbase = (size_t)head * SEQ * DIM;
  const int bb = head >> 4;

  const int nc  = ncomp[bb];
  const int ntb = (nc + 63) >> 6;

  const char* ktb = Kws + ((size_t)(head * NTMAX) << 14);
  const char* vtb = Vws + ((size_t)(head * NTMAX) << 14);

  const int qrow = qblk * 128 + w * 32 + q32;

  // Q fragments: lane holds Q[qrow][d = 16c + 8h + j]
  f16x8 qf[8];
  {
    const float* qp = Qg + hbase + (size_t)qrow * DIM + h * 8;
#pragma unroll
    for (int c = 0; c < 8; ++c) {
      float4 a = *(const float4*)(qp + c * 16);
      float4 b = *(const float4*)(qp + c * 16 + 4);
      f16x8 f;
      f[0]=(f16)a.x; f[1]=(f16)a.y; f[2]=(f16)a.z; f[3]=(f16)a.w;
      f[4]=(f16)b.x; f[5]=(f16)b.y; f[6]=(f16)b.z; f[7]=(f16)b.w;
      qf[c] = f;
    }
  }

  f32x16 oacc[4];
#pragma unroll
  for (int dvt = 0; dvt < 4; ++dvt) oacc[dvt] = (f32x16)(0.f);
  float mrow = -INFINITY, lrow = 0.f;

  // packed P of the previous tile
  uint_t pkPA[2][4], pkPB[2][4];
#pragma unroll
  for (int t2 = 0; t2 < 2; ++t2)
#pragma unroll
    for (int m = 0; m < 4; ++m) { pkPA[t2][m] = 0; pkPB[t2][m] = 0; }

  // prologue: stage K(0)   (256 threads x 4 x 16B = 16KB)
#pragma unroll
  for (int i = 0; i < 4; ++i) {
    int u = i * 256 + tid;
    gload16(ktb + u * 16, &Kb[0][u * 16]);
  }

  int cur = 0;
  for (int t = 0; t < ntb; ++t) {
    // ---- stage K(t+1) into Kb[cur^1], V(t) into Vb[cur] ----
    {
      const int tn = (t + 1 == ntb) ? 0 : t + 1;
      const char* kt2 = ktb + ((size_t)tn << 14);
      const char* vt2 = vtb + ((size_t)t << 14);
      const int nb = cur ^ 1;
#pragma unroll
      for (int i = 0; i < 4; ++i) {
        int u = i * 256 + tid;
        gload16(kt2 + u * 16, &Kb[nb][u * 16]);
      }
#pragma unroll
      for (int i = 0; i < 4; ++i) {
        int u = i * 256 + tid;
        gload16(vt2 + u * 16, &Vb[cur][u * 16]);
      }
    }
    // K(t), V(t-1) were the 8 loads issued last iter; keep this iter's 8 in flight
    asm volatile("s_waitcnt vmcnt(8)" ::: "memory");
    __builtin_amdgcn_s_barrier();
    asm volatile("" ::: "memory");

    // ---- QK^T(t): two interleaved accumulator chains ----
    f32x16 s0, s1;
    {
      const int kb0 = t * 64;
      if (kb0 + 32 <= nc) {
        s0 = (f32x16)(0.f);
      } else {
#pragma unroll
        for (int ri = 0; ri < 16; ++ri)
          s0[ri] = (kb0 + (ri >> 2) * 8 + 4 * h + (ri & 3) < nc) ? 0.f : -1e9f;
      }
      const int kb1 = t * 64 + 32;
      if (kb1 + 32 <= nc) {
        s1 = (f32x16)(0.f);
      } else {
#pragma unroll
        for (int ri = 0; ri < 16; ++ri)
          s1[ri] = (kb1 + (ri >> 2) * 8 + 4 * h + (ri & 3) < nc) ? 0.f : -1e9f;
      }
      const int kr0 = q32,      sw0 = kr0 & 15;
      const int kr1 = 32 + q32, sw1 = kr1 & 15;
      __builtin_amdgcn_s_setprio(1);
#pragma unroll
      for (int c = 0; c < 8; ++c) {
        f16x8 k0 = *(const f16x8*)(&Kb[cur][kr0 * 256 + (((2 * c + h) ^ sw0) << 4)]);
        s0 = __builtin_amdgcn_mfma_f32_32x32x16_f16(k0, qf[c], s0, 0, 0, 0);
        f16x8 k1 = *(const f16x8*)(&Kb[cur][kr1 * 256 + (((2 * c + h) ^ sw1) << 4)]);
        s1 = __builtin_amdgcn_mfma_f32_32x32x16_f16(k1, qf[c], s1, 0, 0, 0);
      }
      __builtin_amdgcn_s_setprio(0);
    }

    // ---- PV(t-1): independent of QK(t)/SM(t) ----
    if (t > 0) {
      f16x8 paf[4];
      build_paf(pkPA, pkPB, paf, h);
      pv_mfma(&Vb[cur ^ 1][0], paf, oacc, q32, h);
    }

    // ---- SM(t): tree max, defer-max rescale, exp, tree sum, pack ----
    {
      float mx[16];
#pragma unroll
      for (int r = 0; r < 16; ++r) mx[r] = fmaxf(s0[r], s1[r]);
#pragma unroll
      for (int r = 0; r < 8; ++r) mx[r] = fmaxf(mx[r], mx[r + 8]);
#pragma unroll
      for (int r = 0; r < 4; ++r) mx[r] = fmaxf(mx[r], mx[r + 4]);
      float pmax = fmaxf(fmaxf(mx[0], mx[1]), fmaxf(mx[2], mx[3]));
      pmax = fmaxf(pmax, __shfl_xor(pmax, 32));

      if (!__all(pmax - mrow <= 8.f)) {          // defer-max (T13)
        float mnew = fmaxf(mrow, pmax);
        float scf = __expf(mrow - mnew);
#pragma unroll
        for (int dvt = 0; dvt < 4; ++dvt)
#pragma unroll
          for (int r = 0; r < 16; ++r) oacc[dvt][r] *= scf;
        lrow *= scf;
        mrow = mnew;
      }

      float ps[16];
#pragma unroll
      for (int r = 0; r < 16; ++r) {
        s0[r] = __expf(s0[r] - mrow);
        s1[r] = __expf(s1[r] - mrow);
        ps[r] = s0[r] + s1[r];
      }
#pragma unroll
      for (int r = 0; r < 8; ++r) ps[r] += ps[r + 8];
#pragma unroll
      for (int r = 0; r < 4; ++r) ps[r] += ps[r + 4];
      float psum = (ps[0] + ps[1]) + (ps[2] + ps[3]);
      psum += __shfl_xor(psum, 32);
      lrow += psum;

#pragma unroll
      for (int m = 0; m < 4; ++m) {
        pkPA[0][m] = __builtin_bit_cast(uint_t,
            __builtin_amdgcn_cvt_pkrtz(s0[4 * m + 0], s0[4 * m + 1]));
        pkPB[0][m] = __builtin_bit_cast(uint_t,
            __builtin_amdgcn_cvt_pkrtz(s0[4 * m + 2], s0[4 * m + 3]));
        pkPA[1][m] = __builtin_bit_cast(uint_t,
            __builtin_amdgcn_cvt_pkrtz(s1[4 * m + 0], s1[4 * m + 1]));
        pkPB[1][m] = __builtin_bit_cast(uint_t,
            __builtin_amdgcn_cvt_pkrtz(s1[4 * m + 2], s1[4 * m + 3]));
      }
    }

    asm volatile("" ::: "memory");
    __builtin_amdgcn_s_barrier();
    asm volatile("" ::: "memory");
    cur ^= 1;
  }

  // ---- epilogue: drain V(ntb-1), final PV, normalize, store ----
  asm volatile("s_waitcnt vmcnt(0)" ::: "memory");
  __builtin_amdgcn_s_barrier();
  asm volatile("" ::: "memory");
  {
    f16x8 paf[4];
    build_paf(pkPA, pkPB, paf, h);
    pv_mfma(&Vb[cur ^ 1][0], paf, oacc, q32, h);
  }

  const float inv = 1.0f / lrow;
  float* op = Og + hbase + (size_t)qrow * DIM;
#pragma unroll
  for (int dvt = 0; dvt < 4; ++dvt)
#pragma unroll
    for (int rq = 0; rq < 4; ++rq) {
      float4 o4;
      o4.x = oacc[dvt][4 * rq + 0] * inv;
      o4.y = oacc[dvt][4 * rq + 1] * inv;
      o4.z = oacc[dvt][4 * rq + 2] * inv;
      o4.w = oacc[dvt][4 * rq + 3] * inv;
      *(float4*)(op + dvt * 32 + rq * 8 + h * 4) = o4;
    }
}

// ---------------- fallback (verified round-1 kernel) for small ws ----------------
#define QT 64
#define P_STRIDE 72
#define VT_STRIDE 76
typedef _Float16 f16x4_t __attribute__((ext_vector_type(4)));
__global__ __launch_bounds__(256, 2)
void attn_fwd_fb(const float* __restrict__ Qg, const float* __restrict__ Kg,
                 const float* __restrict__ Vg, const int* __restrict__ Mg,
                 float* __restrict__ Og) {
  __shared__ __align__(16) ushort_t K_lds[QT * DIM];
  __shared__ __align__(16) ushort_t Vt_lds[DIM * VT_STRIDE];
  __shared__ __align__(16) ushort_t P_lds[QT * P_STRIDE];
  __shared__ int M_lds[KVBLK];
  const int tid  = threadIdx.x;
  const int lane = tid & 63;
  const int w    = tid >> 6;
  const int li   = lane & 15;
  const int g    = lane >> 4;
  const int bid  = blockIdx.x;
  const int nid  = (bid & 7) * 256 + (bid >> 3);
  const int head = nid >> 5;
  const int qblk = nid & 31;
  const size_t hbase = (size_t)head * SEQ * DIM;
  const int bb = head >> 4;
  f16x8 qf[4];
  {
    const float* qp = Qg + hbase + (size_t)(qblk * QT + w * 16 + li) * DIM + g * 8;
#pragma unroll
    for (int d0 = 0; d0 < 4; ++d0) {
      float4 a = *(const float4*)(qp + d0 * 32);
      float4 b = *(const float4*)(qp + d0 * 32 + 4);
      f16x8 f;
      f[0]=(f16)a.x; f[1]=(f16)a.y; f[2]=(f16)a.z; f[3]=(f16)a.w;
      f[4]=(f16)b.x; f[5]=(f16)b.y; f[6]=(f16)b.z; f[7]=(f16)b.w;
      qf[d0] = f;
    }
  }
  float mrow[4], lrow[4];
  f32x4 oacc[8];
#pragma unroll
  for (int r = 0; r < 4; ++r) { mrow[r] = -INFINITY; lrow[r] = 0.f; }
#pragma unroll
  for (int dt = 0; dt < 8; ++dt) oacc[dt] = (f32x4)(0.f);
  for (int t = 0; t < NTMAX; ++t) {
    const int k0 = t * KVBLK;
    __syncthreads();
    {
      const float4* kgp = (const float4*)(Kg + hbase + (size_t)k0 * DIM);
#pragma unroll
      for (int rr = 0; rr < 8; ++rr) {
        int fi = rr * 256 + tid;
        int krow = fi >> 5;
        int d4 = fi & 31;
        float4 v = kgp[fi];
        union { f16 h[4]; uint2 u; } c;
        c.h[0]=(f16)v.x; c.h[1]=(f16)v.y; c.h[2]=(f16)v.z; c.h[3]=(f16)v.w;
        int off = krow * 256 + ((d4 * 8) ^ ((krow & 7) << 4));
        *(uint2*)((char*)K_lds + off) = c.u;
      }
    }
    {
      const float* vgp = Vg + hbase + (size_t)k0 * DIM;
#pragma unroll
      for (int rr = 0; rr < 16; ++rr) {
        int u = rr * 256 + tid;
        int d = u & 127;
        int k2 = (u >> 7) * 2;
        float v0 = vgp[(size_t)k2 * DIM + d];
        float v1 = vgp[(size_t)(k2 + 1) * DIM + d];
        union { f16 h[2]; unsigned int u32; } c;
        c.h[0]=(f16)v0; c.h[1]=(f16)v1;
        *(unsigned int*)(Vt_lds + d * VT_STRIDE + k2) = c.u32;
      }
    }
    if (tid < KVBLK) M_lds[tid] = Mg[(size_t)bb * SEQ + k0 + tid];
    __syncthreads();
    f32x4 sacc[4];
#pragma unroll
    for (int kt = 0; kt < 4; ++kt) sacc[kt] = (f32x4)(0.f);
#pragma unroll
    for (int kt = 0; kt < 4; ++kt) {
      const int krow = kt * 16 + li;
      const int swz = (krow & 7) << 4;
#pragma unroll
      for (int d0 = 0; d0 < 4; ++d0) {
        f16x8 kf = *(const f16x8*)((const char*)K_lds + krow * 256 + ((d0 * 64 + g * 16) ^ swz));
        sacc[kt] = __builtin_amdgcn_mfma_f32_16x16x32_f16(qf[d0], kf, sacc[kt], 0, 0, 0);
      }
    }
    float tmax[4] = {-INFINITY, -INFINITY, -INFINITY, -INFINITY};
#pragma unroll
    for (int kt = 0; kt < 4; ++kt) {
      const bool ok = (M_lds[kt * 16 + li] != 0);
#pragma unroll
      for (int r = 0; r < 4; ++r) {
        float sv = ok ? sacc[kt][r] : -1e9f;
        sacc[kt][r] = sv;
        tmax[r] = fmaxf(tmax[r], sv);
      }
    }
#pragma unroll
    for (int r = 0; r < 4; ++r) {
      tmax[r] = fmaxf(tmax[r], __shfl_xor(tmax[r], 1));
      tmax[r] = fmaxf(tmax[r], __shfl_xor(tmax[r], 2));
      tmax[r] = fmaxf(tmax[r], __shfl_xor(tmax[r], 4));
      tmax[r] = fmaxf(tmax[r], __shfl_xor(tmax[r], 8));
    }
    float sc[4], psum[4];
#pragma unroll
    for (int r = 0; r < 4; ++r) {
      float mnew = fmaxf(mrow[r], tmax[r]);
      sc[r] = __expf(mrow[r] - mnew);
      mrow[r] = mnew;
      psum[r] = 0.f;
    }
#pragma unroll
    for (int dt = 0; dt < 8; ++dt)
#pragma unroll
      for (int r = 0; r < 4; ++r) oacc[dt][r] *= sc[r];
#pragma unroll
    for (int kt = 0; kt < 4; ++kt) {
#pragma unroll
      for (int r = 0; r < 4; ++r) {
        float p = __expf(sacc[kt][r] - mrow[r]);
        psum[r] += p;
        P_lds[(w * 16 + g * 4 + r) * P_STRIDE + kt * 16 + li] =
            __builtin_bit_cast(ushort_t, (f16)p);
      }
    }
#pragma unroll
    for (int r = 0; r < 4; ++r) {
      psum[r] += __shfl_xor(psum[r], 1);
      psum[r] += __shfl_xor(psum[r], 2);
      psum[r] += __shfl_xor(psum[r], 4);
      psum[r] += __shfl_xor(psum[r], 8);
      lrow[r] = lrow[r] * sc[r] + psum[r];
    }
#pragma unroll
    for (int c = 0; c < 2; ++c) {
      f16x8 pa = *(const f16x8*)(P_lds + (w * 16 + li) * P_STRIDE + c * 32 + g * 8);
#pragma unroll
      for (int dt = 0; dt < 8; ++dt) {
        const ushort_t* vp = Vt_lds + (dt * 16 + li) * VT_STRIDE + c * 32 + g * 8;
        f16x4_t v0 = *(const f16x4_t*)vp;
        f16x4_t v1 = *(const f16x4_t*)(vp + 4);
        f16x8 vf;
        vf[0]=v0[0]; vf[1]=v0[1]; vf[2]=v0[2]; vf[3]=v0[3];
        vf[4]=v1[0]; vf[5]=v1[1]; vf[6]=v1[2]; vf[7]=v1[3];
        oacc[dt] = __builtin_amdgcn_mfma_f32_16x16x32_f16(pa, vf, oacc[dt], 0, 0, 0);
      }
    }
  }
#pragma unroll
  for (int r = 0; r < 4; ++r) {
    float inv = 1.0f / lrow[r];
    float* op = Og + hbase + (size_t)(qblk * QT + w * 16 + g * 4 + r) * DIM + li;
#pragma unroll
    for (int dt = 0; dt < 8; ++dt) op[dt * 16] = oacc[dt][r] * inv;
  }
}

extern "C" void kernel_launch(void* const* d_in, const int* in_sizes, int n_in,
                              void* d_out, int out_size, void* d_ws, size_t ws_size,
                              hipStream_t stream) {
  (void)in_sizes; (void)n_in; (void)out_size;
  const float* Q = (const float*)d_in[0];
  const float* K = (const float*)d_in[1];
  const float* V = (const float*)d_in[2];
  const int*   M = (const int*)d_in[3];
  float*       O = (float*)d_out;

  const size_t half = (size_t)2048 * TILE_BYTES;         // 33.5 MB each
  const size_t cidx_off  = 2 * half;
  const size_t ncomp_off = cidx_off + (size_t)4 * SEQ * sizeof(int);
  const size_t need = ncomp_off + 4 * sizeof(int);

  if (ws_size >= need) {
    char* Kws = (char*)d_ws;
    char* Vws = Kws + half;
    int*  cidx  = (int*)((char*)d_ws + cidx_off);
    int*  ncomp = (int*)((char*)d_ws + ncomp_off);
    scan_mask<<<dim3(4), dim3(64), 0, stream>>>(M, cidx, ncomp);
    prep_kv<<<dim3(4096), dim3(256), 0, stream>>>(K, Kws, V, Vws, cidx, ncomp);
    attn_main32<<<dim3(1024), dim3(256), 0, stream>>>(Q, Kws, Vws, ncomp, O);
  } else {
    attn_fwd_fb<<<dim3(2048), dim3(256), 0, stream>>>(Q, K, V, M, O);
  }
}